// Round 1
// baseline (933.246 us; speedup 1.0000x reference)
//
#include <hip/hip_runtime.h>
#include <hip/hip_fp16.h>

typedef _Float16 half_t;
typedef _Float16 half8 __attribute__((ext_vector_type(8)));
typedef float floatx4 __attribute__((ext_vector_type(4)));

// ---- sizes ----
#define T_STEPS 300
#define NMB     1024           // N*M batch
#define HID     128
#define GATES   512
#define XT_ROWS (T_STEPS*NMB + 16)   // +16 pad so A-fragment row reads never fault

// ws layout (bytes)
#define XT_OFF   0ULL
#define XT_BYTES ((unsigned long long)XT_ROWS*64*2)          // 39,323,648
#define HS0_OFF  (XT_OFF + XT_BYTES)
#define HS0_BYTES ((unsigned long long)XT_ROWS*128*2)        // 78,647,296
#define WC_OFF   (HS0_OFF + HS0_BYTES)                       // 117,970,944
#define WC_BYTES (512ULL*64*4)
#define BC_OFF   (WC_OFF + WC_BYTES)                         // 118,102,016

// L_hat = -D^-1/2 A D^-1/2 for the hardcoded 15-node skeleton (row=dst, col=src)
#define S2 0.70710678118654752f
#define QH 0.5f
#define UU 0.40824829046386302f
#define TH 0.33333333333333333f
__constant__ float LHAT[225] = {
  0,0,-S2,0,0,0,0,0,0,0,0,0,0,0,0,
  0,0,0,-S2,0,0,0,0,0,0,0,0,0,0,0,
  -S2,0,0,0,-QH,0,0,0,0,0,0,0,0,0,0,
  0,-S2,0,0,0,-QH,0,0,0,0,0,0,0,0,0,
  0,0,-QH,0,0,0,0,0,0,0,0,0,0,0,-UU,
  0,0,0,-QH,0,0,0,0,0,0,0,0,0,0,-UU,
  0,0,0,0,0,0,0,0,-S2,0,0,0,0,0,0,
  0,0,0,0,0,0,0,0,0,-S2,0,0,0,0,0,
  0,0,0,0,0,0,-S2,0,0,0,-QH,0,0,0,0,
  0,0,0,0,0,0,0,-S2,0,0,0,-QH,0,0,0,
  0,0,0,0,0,0,0,0,-QH,0,0,0,0,-UU,0,
  0,0,0,0,0,0,0,0,0,-QH,0,0,0,-UU,0,
  0,0,0,0,0,0,0,0,0,0,0,0,0,0,0,
  0,0,0,0,0,0,0,0,0,0,-UU,-UU,0,0,0,
  0,0,0,0,-UU,-UU,0,0,0,0,0,0,0,-TH,0
};

__device__ __forceinline__ float fsig(float x) { return 1.f/(1.f+__expf(-x)); }
__device__ __forceinline__ float ftanh(float x) {
  x = fminf(10.f, fmaxf(-10.f, x));
  float e = __expf(-2.f*x);
  return (1.f-e)/(1.f+e);
}
__device__ __forceinline__ half8 load_w8(const float* p) {
  const float4* q = (const float4*)p;
  float4 a = q[0], b = q[1];
  half8 f;
  f[0]=(half_t)a.x; f[1]=(half_t)a.y; f[2]=(half_t)a.z; f[3]=(half_t)a.w;
  f[4]=(half_t)b.x; f[5]=(half_t)b.y; f[6]=(half_t)b.z; f[7]=(half_t)b.w;
  return f;
}

// ---- K0: fold ChebConv into the layer-0 input projection: Wcomb[512][64], bias_comb[512]
__global__ void k_prep(const float* __restrict__ w0, const float* __restrict__ w1,
                       const float* __restrict__ cb, const float* __restrict__ wih0,
                       const float* __restrict__ bih0, const float* __restrict__ bhh0,
                       float* __restrict__ wcomb, float* __restrict__ biasc) {
  const int n = threadIdx.x; // 512 threads, 1 block
  float wrow[45];
  #pragma unroll
  for (int i=0;i<45;i++) wrow[i] = wih0[n*45+i];
  float P[45];
  #pragma unroll
  for (int i=0;i<15;i++)
    #pragma unroll
    for (int c=0;c<3;c++) {
      float s = 0.f;
      #pragma unroll
      for (int cp=0;cp<3;cp++) s += wrow[i*3+cp]*w1[cp*3+c];
      P[i*3+c] = s;
    }
  #pragma unroll
  for (int j=0;j<15;j++)
    #pragma unroll
    for (int c=0;c<3;c++) {
      float s = 0.f;
      #pragma unroll
      for (int cp=0;cp<3;cp++) s += wrow[j*3+cp]*w0[cp*3+c];
      #pragma unroll
      for (int i=0;i<15;i++) s += LHAT[i*15+j]*P[i*3+c];
      wcomb[n*64 + j*3+c] = s;
    }
  for (int k=45;k<64;k++) wcomb[n*64+k] = 0.f;
  float b = bih0[n] + bhh0[n];
  #pragma unroll
  for (int i=0;i<15;i++)
    #pragma unroll
    for (int cp=0;cp<3;cp++) b += wrow[i*3+cp]*cb[cp];
  biasc[n] = b;
}

// ---- K0b: x1 [N,C,T,V,M] fp32 -> xt [t*1024+nm][64] fp16 (features v*3+c, 45 valid)
__global__ void k_xpose(const float* __restrict__ x1, half_t* __restrict__ xt) {
  const int id = blockIdx.x*256 + threadIdx.x;   // exactly 512*3*300*15 = 6,912,000
  const int v  = id % 15;
  const int r1 = id / 15;
  const int t  = r1 % 300;
  const int r2 = r1 / 300;
  const int c  = r2 % 3;
  const int n  = r2 / 3;
  const float2 f = ((const float2*)x1)[id];      // m=0,1 pair, coalesced
  const size_t row = (size_t)t*NMB + n*2;
  xt[row*64     + v*3 + c] = (half_t)f.x;
  xt[(row+1)*64 + v*3 + c] = (half_t)f.y;
}

// ---- KA: layer-0 LSTM recurrence. 256 WGs x 512 threads; 4 batch rows per WG.
// Per wave: 64 gate cols; weights (Whh0 K=128, Wcomb K=64) resident in VGPRs as MFMA B-frags.
__launch_bounds__(512, 2)
__global__ void k_lstm0(const half_t* __restrict__ xt, const float* __restrict__ wcomb,
                        const float* __restrict__ biasc, const float* __restrict__ whh0,
                        half_t* __restrict__ hs0) {
  __shared__ __align__(16) half_t h_lds[16*136];   // 16 rows (4 valid), pad to 136 halfs
  __shared__ float gates_lds[4*516];
  const int tid = threadIdx.x;
  const int wave = tid>>6, lane = tid&63, quad = lane>>4, l16 = lane&15;
  const int nm0 = blockIdx.x*4;
  for (int i=tid; i<16*136; i+=512) h_lds[i] = (half_t)0.f;

  half8 whhF[4][4];  // [nt][kc] B-frags: B[k][n] = Whh0[n][k]
  half8 wcF [4][2];
  #pragma unroll
  for (int nt=0; nt<4; nt++) {
    const int col = (wave*4+nt)*16 + l16;
    #pragma unroll
    for (int kc=0; kc<4; kc++) whhF[nt][kc] = load_w8(whh0 + col*128 + kc*32 + quad*8);
    #pragma unroll
    for (int kc=0; kc<2; kc++) wcF[nt][kc]  = load_w8(wcomb + col*64 + kc*32 + quad*8);
  }
  const int rr = tid>>7, kk = tid&127;
  const float bi = biasc[kk], bf = biasc[128+kk], bg = biasc[256+kk], bo = biasc[384+kk];
  float cst = 0.f;

  half8 xv[2], xvn[2];
  { const size_t row = (size_t)nm0 + l16;   // t = 0
    xv[0] = *(const half8*)(xt + row*64 +      quad*8);
    xv[1] = *(const half8*)(xt + row*64 + 32 + quad*8);
  }
  __syncthreads();

  for (int t=0; t<T_STEPS; t++) {
    const int tn = (t+1 < T_STEPS) ? t+1 : T_STEPS-1;
    { const size_t row = (size_t)tn*NMB + nm0 + l16;     // prefetch next step's x
      xvn[0] = *(const half8*)(xt + row*64 +      quad*8);
      xvn[1] = *(const half8*)(xt + row*64 + 32 + quad*8);
    }
    half8 hA[4];
    #pragma unroll
    for (int kc=0; kc<4; kc++)
      hA[kc] = *(const half8*)(h_lds + l16*136 + kc*32 + quad*8);

    floatx4 acc[4];
    #pragma unroll
    for (int nt=0; nt<4; nt++) {
      floatx4 a = {0.f,0.f,0.f,0.f};
      a = __builtin_amdgcn_mfma_f32_16x16x32_f16(xv[0], wcF[nt][0], a, 0,0,0);
      a = __builtin_amdgcn_mfma_f32_16x16x32_f16(xv[1], wcF[nt][1], a, 0,0,0);
      #pragma unroll
      for (int kc=0; kc<4; kc++)
        a = __builtin_amdgcn_mfma_f32_16x16x32_f16(hA[kc], whhF[nt][kc], a, 0,0,0);
      acc[nt] = a;
    }
    if (quad == 0) {  // rows 0..3 live in quad 0: col=lane&15, row=reg
      #pragma unroll
      for (int nt=0; nt<4; nt++) {
        const int col = wave*64 + nt*16 + l16;
        #pragma unroll
        for (int reg=0; reg<4; reg++) gates_lds[reg*516 + col] = acc[nt][reg];
      }
    }
    __syncthreads();
    {
      const float gi = gates_lds[rr*516 +       kk] + bi;
      const float gf = gates_lds[rr*516 + 128 + kk] + bf;
      const float gg = gates_lds[rr*516 + 256 + kk] + bg;
      const float go = gates_lds[rr*516 + 384 + kk] + bo;
      const float si = fsig(gi), sf = fsig(gf), sg = ftanh(gg), so = fsig(go);
      cst = sf*cst + si*sg;
      const float h = so*ftanh(cst);
      h_lds[rr*136 + kk] = (half_t)h;
      hs0[((size_t)t*NMB + nm0 + rr)*128 + kk] = (half_t)h;
    }
    xv[0] = xvn[0]; xv[1] = xvn[1];
    __syncthreads();
  }
}

// ---- KB: layer-1 LSTM (input GEMM on the fly from hs0) + FC + softmax
__launch_bounds__(512, 2)
__global__ void k_lstm1(const half_t* __restrict__ hs0, const float* __restrict__ wih1,
                        const float* __restrict__ whh1, const float* __restrict__ bih1,
                        const float* __restrict__ bhh1, const float* __restrict__ fcw,
                        const float* __restrict__ fcb, float* __restrict__ out) {
  __shared__ __align__(16) half_t h_lds[16*136];
  __shared__ float gates_lds[4*516];
  __shared__ float logits_lds[240];
  const int tid = threadIdx.x;
  const int wave = tid>>6, lane = tid&63, quad = lane>>4, l16 = lane&15;
  const int nm0 = blockIdx.x*4;
  for (int i=tid; i<16*136; i+=512) h_lds[i] = (half_t)0.f;

  half8 wxF[4][4], whF[4][4];
  #pragma unroll
  for (int nt=0; nt<4; nt++) {
    const int col = (wave*4+nt)*16 + l16;
    #pragma unroll
    for (int kc=0; kc<4; kc++) {
      wxF[nt][kc] = load_w8(wih1 + col*128 + kc*32 + quad*8);
      whF[nt][kc] = load_w8(whh1 + col*128 + kc*32 + quad*8);
    }
  }
  const int rr = tid>>7, kk = tid&127;
  const float bi = bih1[kk]      + bhh1[kk];
  const float bf = bih1[128+kk]  + bhh1[128+kk];
  const float bg = bih1[256+kk]  + bhh1[256+kk];
  const float bo = bih1[384+kk]  + bhh1[384+kk];
  float cst = 0.f;

  half8 xv[4], xvn[4];
  { const size_t row = (size_t)nm0 + l16;   // t = 0
    #pragma unroll
    for (int kc=0; kc<4; kc++) xv[kc] = *(const half8*)(hs0 + row*128 + kc*32 + quad*8);
  }
  __syncthreads();

  for (int t=0; t<T_STEPS; t++) {
    const int tn = (t+1 < T_STEPS) ? t+1 : T_STEPS-1;
    { const size_t row = (size_t)tn*NMB + nm0 + l16;
      #pragma unroll
      for (int kc=0; kc<4; kc++) xvn[kc] = *(const half8*)(hs0 + row*128 + kc*32 + quad*8);
    }
    half8 hA[4];
    #pragma unroll
    for (int kc=0; kc<4; kc++)
      hA[kc] = *(const half8*)(h_lds + l16*136 + kc*32 + quad*8);

    floatx4 acc[4];
    #pragma unroll
    for (int nt=0; nt<4; nt++) {
      floatx4 a = {0.f,0.f,0.f,0.f};
      #pragma unroll
      for (int kc=0; kc<4; kc++)
        a = __builtin_amdgcn_mfma_f32_16x16x32_f16(xv[kc], wxF[nt][kc], a, 0,0,0);
      #pragma unroll
      for (int kc=0; kc<4; kc++)
        a = __builtin_amdgcn_mfma_f32_16x16x32_f16(hA[kc], whF[nt][kc], a, 0,0,0);
      acc[nt] = a;
    }
    if (quad == 0) {
      #pragma unroll
      for (int nt=0; nt<4; nt++) {
        const int col = wave*64 + nt*16 + l16;
        #pragma unroll
        for (int reg=0; reg<4; reg++) gates_lds[reg*516 + col] = acc[nt][reg];
      }
    }
    __syncthreads();
    {
      const float gi = gates_lds[rr*516 +       kk] + bi;
      const float gf = gates_lds[rr*516 + 128 + kk] + bf;
      const float gg = gates_lds[rr*516 + 256 + kk] + bg;
      const float go = gates_lds[rr*516 + 384 + kk] + bo;
      const float si = fsig(gi), sf = fsig(gf), sg = ftanh(gg), so = fsig(go);
      cst = sf*cst + si*sg;
      h_lds[rr*136 + kk] = (half_t)(so*ftanh(cst));
    }
    #pragma unroll
    for (int kc=0; kc<4; kc++) xv[kc] = xvn[kc];
    __syncthreads();
  }

  // FC (60 classes) + softmax, h_last is in h_lds rows 0..3
  if (tid < 240) {
    const int r2 = tid/60, cls = tid%60;
    float s = fcb[cls];
    for (int k2=0; k2<128; k2++) s += (float)h_lds[r2*136+k2] * fcw[cls*128+k2];
    logits_lds[r2*60+cls] = s;
  }
  __syncthreads();
  if (tid < 4) {
    float m = -1e30f;
    for (int j=0; j<60; j++) m = fmaxf(m, logits_lds[tid*60+j]);
    float s = 0.f;
    for (int j=0; j<60; j++) s += __expf(logits_lds[tid*60+j]-m);
    const float inv = 1.f/s;
    for (int j=0; j<60; j++) out[(nm0+tid)*60+j] = __expf(logits_lds[tid*60+j]-m)*inv;
  }
}

extern "C" void kernel_launch(void* const* d_in, const int* in_sizes, int n_in,
                              void* d_out, int out_size, void* d_ws, size_t ws_size,
                              hipStream_t stream) {
  const float* x1      = (const float*)d_in[0];
  const float* cheb_w0 = (const float*)d_in[2];
  const float* cheb_w1 = (const float*)d_in[3];
  const float* cheb_b  = (const float*)d_in[4];
  const float* wih0    = (const float*)d_in[5];
  const float* whh0    = (const float*)d_in[6];
  const float* bih0    = (const float*)d_in[7];
  const float* bhh0    = (const float*)d_in[8];
  const float* wih1    = (const float*)d_in[9];
  const float* whh1    = (const float*)d_in[10];
  const float* bih1    = (const float*)d_in[11];
  const float* bhh1    = (const float*)d_in[12];
  const float* fc_w    = (const float*)d_in[13];
  const float* fc_b    = (const float*)d_in[14];

  char* ws = (char*)d_ws;
  half_t* xt    = (half_t*)(ws + XT_OFF);
  half_t* hs0   = (half_t*)(ws + HS0_OFF);
  float*  wcomb = (float*)(ws + WC_OFF);
  float*  biasc = (float*)(ws + BC_OFF);

  k_prep <<<dim3(1),     dim3(512), 0, stream>>>(cheb_w0, cheb_w1, cheb_b, wih0, bih0, bhh0, wcomb, biasc);
  k_xpose<<<dim3(27000), dim3(256), 0, stream>>>(x1, xt);
  k_lstm0<<<dim3(256),   dim3(512), 0, stream>>>(xt, wcomb, biasc, whh0, hs0);
  k_lstm1<<<dim3(256),   dim3(512), 0, stream>>>(hs0, wih1, whh1, bih1, bhh1, fc_w, fc_b, (float*)d_out);
}

// Round 2
// 907.547 us; speedup vs baseline: 1.0283x; 1.0283x over previous
//
#include <hip/hip_runtime.h>
#include <hip/hip_fp16.h>

typedef _Float16 half_t;
typedef _Float16 half8 __attribute__((ext_vector_type(8)));
typedef float floatx4 __attribute__((ext_vector_type(4)));

// ---- sizes ----
#define T_STEPS 300
#define NMB     1024           // N*M batch
#define HID     128
#define GATES   512
#define XT_ROWS (T_STEPS*NMB + 16)   // +16 pad so A-fragment row reads never fault

// ws layout (bytes)
#define XT_OFF   0ULL
#define XT_BYTES ((unsigned long long)XT_ROWS*64*2)          // 39,323,648
#define HS0_OFF  (XT_OFF + XT_BYTES)
#define HS0_BYTES ((unsigned long long)XT_ROWS*128*2)        // 78,647,296
#define WC_OFF   (HS0_OFF + HS0_BYTES)                       // 117,970,944
#define WC_BYTES (512ULL*64*4)
#define BC_OFF   (WC_OFF + WC_BYTES)                         // 118,102,016

// L_hat = -D^-1/2 A D^-1/2 for the hardcoded 15-node skeleton (row=dst, col=src)
#define S2 0.70710678118654752f
#define QH 0.5f
#define UU 0.40824829046386302f
#define TH 0.33333333333333333f
__constant__ float LHAT[225] = {
  0,0,-S2,0,0,0,0,0,0,0,0,0,0,0,0,
  0,0,0,-S2,0,0,0,0,0,0,0,0,0,0,0,
  -S2,0,0,0,-QH,0,0,0,0,0,0,0,0,0,0,
  0,-S2,0,0,0,-QH,0,0,0,0,0,0,0,0,0,
  0,0,-QH,0,0,0,0,0,0,0,0,0,0,0,-UU,
  0,0,0,-QH,0,0,0,0,0,0,0,0,0,0,-UU,
  0,0,0,0,0,0,0,0,-S2,0,0,0,0,0,0,
  0,0,0,0,0,0,0,0,0,-S2,0,0,0,0,0,
  0,0,0,0,0,0,-S2,0,0,0,-QH,0,0,0,0,
  0,0,0,0,0,0,0,-S2,0,0,0,-QH,0,0,0,
  0,0,0,0,0,0,0,0,-QH,0,0,0,0,-UU,0,
  0,0,0,0,0,0,0,0,0,-QH,0,0,0,-UU,0,
  0,0,0,0,0,0,0,0,0,0,0,0,0,0,0,
  0,0,0,0,0,0,0,0,0,0,-UU,-UU,0,0,0,
  0,0,0,0,-UU,-UU,0,0,0,0,0,0,0,-TH,0
};

// Fast gate math: v_exp_f32 + v_rcp_f32 (approx, ~1 ulp) instead of the
// precise-division sequence (~10 VALU ops each). absmax margin is ~5x.
__device__ __forceinline__ float frcp(float x)  { return __builtin_amdgcn_rcpf(x); }
__device__ __forceinline__ float fsig(float x)  { return frcp(1.f + __expf(-x)); }
__device__ __forceinline__ float ftanh(float x) { return 2.f*frcp(1.f + __expf(-2.f*x)) - 1.f; }

__device__ __forceinline__ half8 load_w8(const float* p) {
  const float4* q = (const float4*)p;
  float4 a = q[0], b = q[1];
  half8 f;
  f[0]=(half_t)a.x; f[1]=(half_t)a.y; f[2]=(half_t)a.z; f[3]=(half_t)a.w;
  f[4]=(half_t)b.x; f[5]=(half_t)b.y; f[6]=(half_t)b.z; f[7]=(half_t)b.w;
  return f;
}

// ---- K0: fold ChebConv into the layer-0 input projection: Wcomb[512][64], bias_comb[512]
__global__ void k_prep(const float* __restrict__ w0, const float* __restrict__ w1,
                       const float* __restrict__ cb, const float* __restrict__ wih0,
                       const float* __restrict__ bih0, const float* __restrict__ bhh0,
                       float* __restrict__ wcomb, float* __restrict__ biasc) {
  const int n = threadIdx.x; // 512 threads, 1 block
  float wrow[45];
  #pragma unroll
  for (int i=0;i<45;i++) wrow[i] = wih0[n*45+i];
  float P[45];
  #pragma unroll
  for (int i=0;i<15;i++)
    #pragma unroll
    for (int c=0;c<3;c++) {
      float s = 0.f;
      #pragma unroll
      for (int cp=0;cp<3;cp++) s += wrow[i*3+cp]*w1[cp*3+c];
      P[i*3+c] = s;
    }
  #pragma unroll
  for (int j=0;j<15;j++)
    #pragma unroll
    for (int c=0;c<3;c++) {
      float s = 0.f;
      #pragma unroll
      for (int cp=0;cp<3;cp++) s += wrow[j*3+cp]*w0[cp*3+c];
      #pragma unroll
      for (int i=0;i<15;i++) s += LHAT[i*15+j]*P[i*3+c];
      wcomb[n*64 + j*3+c] = s;
    }
  for (int k=45;k<64;k++) wcomb[n*64+k] = 0.f;
  float b = bih0[n] + bhh0[n];
  #pragma unroll
  for (int i=0;i<15;i++)
    #pragma unroll
    for (int cp=0;cp<3;cp++) b += wrow[i*3+cp]*cb[cp];
  biasc[n] = b;
}

// ---- K0b: x1 [N,C,T,V,M] fp32 -> xt [t*1024+nm][64] fp16 (features v*3+c, 45 valid)
__global__ void k_xpose(const float* __restrict__ x1, half_t* __restrict__ xt) {
  const int id = blockIdx.x*256 + threadIdx.x;   // exactly 512*3*300*15 = 6,912,000
  const int v  = id % 15;
  const int r1 = id / 15;
  const int t  = r1 % 300;
  const int r2 = r1 / 300;
  const int c  = r2 % 3;
  const int n  = r2 / 3;
  const float2 f = ((const float2*)x1)[id];      // m=0,1 pair, coalesced
  const size_t row = (size_t)t*NMB + n*2;
  xt[row*64     + v*3 + c] = (half_t)f.x;
  xt[(row+1)*64 + v*3 + c] = (half_t)f.y;
}

// ---- KA: layer-0 LSTM recurrence. 256 WGs x 512 threads; 4 batch rows per WG.
// Per wave: 64 gate cols; weights (Whh0 K=128, Wcomb K=64) resident in VGPRs as MFMA B-frags.
__launch_bounds__(512, 2)
__global__ void k_lstm0(const half_t* __restrict__ xt, const float* __restrict__ wcomb,
                        const float* __restrict__ biasc, const float* __restrict__ whh0,
                        half_t* __restrict__ hs0) {
  __shared__ __align__(16) half_t h_lds[16*136];   // 16 rows (4 valid), pad to 136 halfs
  __shared__ float gates_lds[4*516];
  const int tid = threadIdx.x;
  const int wave = tid>>6, lane = tid&63, quad = lane>>4, l16 = lane&15;
  const int nm0 = blockIdx.x*4;
  for (int i=tid; i<16*136; i+=512) h_lds[i] = (half_t)0.f;

  half8 whhF[4][4];  // [nt][kc] B-frags: B[k][n] = Whh0[n][k]
  half8 wcF [4][2];
  #pragma unroll
  for (int nt=0; nt<4; nt++) {
    const int col = (wave*4+nt)*16 + l16;
    #pragma unroll
    for (int kc=0; kc<4; kc++) whhF[nt][kc] = load_w8(whh0 + col*128 + kc*32 + quad*8);
    #pragma unroll
    for (int kc=0; kc<2; kc++) wcF[nt][kc]  = load_w8(wcomb + col*64 + kc*32 + quad*8);
  }
  const int rr = tid>>7, kk = tid&127;
  const float bi = biasc[kk], bf = biasc[128+kk], bg = biasc[256+kk], bo = biasc[384+kk];
  float cst = 0.f;

  half8 xv[2], xvn[2];
  { const size_t row = (size_t)nm0 + l16;   // t = 0
    xv[0] = *(const half8*)(xt + row*64 +      quad*8);
    xv[1] = *(const half8*)(xt + row*64 + 32 + quad*8);
  }
  __syncthreads();

  for (int t=0; t<T_STEPS; t++) {
    const int tn = (t+1 < T_STEPS) ? t+1 : T_STEPS-1;
    { const size_t row = (size_t)tn*NMB + nm0 + l16;     // prefetch next step's x
      xvn[0] = *(const half8*)(xt + row*64 +      quad*8);
      xvn[1] = *(const half8*)(xt + row*64 + 32 + quad*8);
    }
    half8 hA[4];
    #pragma unroll
    for (int kc=0; kc<4; kc++)
      hA[kc] = *(const half8*)(h_lds + l16*136 + kc*32 + quad*8);

    floatx4 acc[4];
    #pragma unroll
    for (int nt=0; nt<4; nt++) {
      floatx4 a = {0.f,0.f,0.f,0.f};
      a = __builtin_amdgcn_mfma_f32_16x16x32_f16(xv[0], wcF[nt][0], a, 0,0,0);
      a = __builtin_amdgcn_mfma_f32_16x16x32_f16(xv[1], wcF[nt][1], a, 0,0,0);
      #pragma unroll
      for (int kc=0; kc<4; kc++)
        a = __builtin_amdgcn_mfma_f32_16x16x32_f16(hA[kc], whhF[nt][kc], a, 0,0,0);
      acc[nt] = a;
    }
    if (quad == 0) {  // rows 0..3 live in quad 0: col=lane&15, row=reg
      #pragma unroll
      for (int nt=0; nt<4; nt++) {
        const int col = wave*64 + nt*16 + l16;
        #pragma unroll
        for (int reg=0; reg<4; reg++) gates_lds[reg*516 + col] = acc[nt][reg];
      }
    }
    __syncthreads();
    {
      const float gi = gates_lds[rr*516 +       kk] + bi;
      const float gf = gates_lds[rr*516 + 128 + kk] + bf;
      const float gg = gates_lds[rr*516 + 256 + kk] + bg;
      const float go = gates_lds[rr*516 + 384 + kk] + bo;
      const float si = fsig(gi), sf = fsig(gf), sg = ftanh(gg), so = fsig(go);
      cst = sf*cst + si*sg;
      const float h = so*ftanh(cst);
      h_lds[rr*136 + kk] = (half_t)h;
      hs0[((size_t)t*NMB + nm0 + rr)*128 + kk] = (half_t)h;
    }
    xv[0] = xvn[0]; xv[1] = xvn[1];
    __syncthreads();
  }
}

// ---- KB: layer-1 LSTM (input GEMM on the fly from hs0) + FC + softmax
__launch_bounds__(512, 2)
__global__ void k_lstm1(const half_t* __restrict__ hs0, const float* __restrict__ wih1,
                        const float* __restrict__ whh1, const float* __restrict__ bih1,
                        const float* __restrict__ bhh1, const float* __restrict__ fcw,
                        const float* __restrict__ fcb, float* __restrict__ out) {
  __shared__ __align__(16) half_t h_lds[16*136];
  __shared__ float gates_lds[4*516];
  __shared__ float logits_lds[240];
  const int tid = threadIdx.x;
  const int wave = tid>>6, lane = tid&63, quad = lane>>4, l16 = lane&15;
  const int nm0 = blockIdx.x*4;
  for (int i=tid; i<16*136; i+=512) h_lds[i] = (half_t)0.f;

  half8 wxF[4][4], whF[4][4];
  #pragma unroll
  for (int nt=0; nt<4; nt++) {
    const int col = (wave*4+nt)*16 + l16;
    #pragma unroll
    for (int kc=0; kc<4; kc++) {
      wxF[nt][kc] = load_w8(wih1 + col*128 + kc*32 + quad*8);
      whF[nt][kc] = load_w8(whh1 + col*128 + kc*32 + quad*8);
    }
  }
  const int rr = tid>>7, kk = tid&127;
  const float bi = bih1[kk]      + bhh1[kk];
  const float bf = bih1[128+kk]  + bhh1[128+kk];
  const float bg = bih1[256+kk]  + bhh1[256+kk];
  const float bo = bih1[384+kk]  + bhh1[384+kk];
  float cst = 0.f;

  half8 xv[4], xvn[4];
  { const size_t row = (size_t)nm0 + l16;   // t = 0
    #pragma unroll
    for (int kc=0; kc<4; kc++) xv[kc] = *(const half8*)(hs0 + row*128 + kc*32 + quad*8);
  }
  __syncthreads();

  for (int t=0; t<T_STEPS; t++) {
    const int tn = (t+1 < T_STEPS) ? t+1 : T_STEPS-1;
    { const size_t row = (size_t)tn*NMB + nm0 + l16;
      #pragma unroll
      for (int kc=0; kc<4; kc++) xvn[kc] = *(const half8*)(hs0 + row*128 + kc*32 + quad*8);
    }
    half8 hA[4];
    #pragma unroll
    for (int kc=0; kc<4; kc++)
      hA[kc] = *(const half8*)(h_lds + l16*136 + kc*32 + quad*8);

    floatx4 acc[4];
    #pragma unroll
    for (int nt=0; nt<4; nt++) {
      floatx4 a = {0.f,0.f,0.f,0.f};
      #pragma unroll
      for (int kc=0; kc<4; kc++)
        a = __builtin_amdgcn_mfma_f32_16x16x32_f16(xv[kc], wxF[nt][kc], a, 0,0,0);
      #pragma unroll
      for (int kc=0; kc<4; kc++)
        a = __builtin_amdgcn_mfma_f32_16x16x32_f16(hA[kc], whF[nt][kc], a, 0,0,0);
      acc[nt] = a;
    }
    if (quad == 0) {
      #pragma unroll
      for (int nt=0; nt<4; nt++) {
        const int col = wave*64 + nt*16 + l16;
        #pragma unroll
        for (int reg=0; reg<4; reg++) gates_lds[reg*516 + col] = acc[nt][reg];
      }
    }
    __syncthreads();
    {
      const float gi = gates_lds[rr*516 +       kk] + bi;
      const float gf = gates_lds[rr*516 + 128 + kk] + bf;
      const float gg = gates_lds[rr*516 + 256 + kk] + bg;
      const float go = gates_lds[rr*516 + 384 + kk] + bo;
      const float si = fsig(gi), sf = fsig(gf), sg = ftanh(gg), so = fsig(go);
      cst = sf*cst + si*sg;
      h_lds[rr*136 + kk] = (half_t)(so*ftanh(cst));
    }
    #pragma unroll
    for (int kc=0; kc<4; kc++) xv[kc] = xvn[kc];
    __syncthreads();
  }

  // FC (60 classes) + softmax, h_last is in h_lds rows 0..3
  if (tid < 240) {
    const int r2 = tid/60, cls = tid%60;
    float s = fcb[cls];
    for (int k2=0; k2<128; k2++) s += (float)h_lds[r2*136+k2] * fcw[cls*128+k2];
    logits_lds[r2*60+cls] = s;
  }
  __syncthreads();
  if (tid < 4) {
    float m = -1e30f;
    for (int j=0; j<60; j++) m = fmaxf(m, logits_lds[tid*60+j]);
    float s = 0.f;
    for (int j=0; j<60; j++) s += __expf(logits_lds[tid*60+j]-m);
    const float inv = frcp(s);
    for (int j=0; j<60; j++) out[(nm0+tid)*60+j] = __expf(logits_lds[tid*60+j]-m)*inv;
  }
}

extern "C" void kernel_launch(void* const* d_in, const int* in_sizes, int n_in,
                              void* d_out, int out_size, void* d_ws, size_t ws_size,
                              hipStream_t stream) {
  const float* x1      = (const float*)d_in[0];
  const float* cheb_w0 = (const float*)d_in[2];
  const float* cheb_w1 = (const float*)d_in[3];
  const float* cheb_b  = (const float*)d_in[4];
  const float* wih0    = (const float*)d_in[5];
  const float* whh0    = (const float*)d_in[6];
  const float* bih0    = (const float*)d_in[7];
  const float* bhh0    = (const float*)d_in[8];
  const float* wih1    = (const float*)d_in[9];
  const float* whh1    = (const float*)d_in[10];
  const float* bih1    = (const float*)d_in[11];
  const float* bhh1    = (const float*)d_in[12];
  const float* fc_w    = (const float*)d_in[13];
  const float* fc_b    = (const float*)d_in[14];

  char* ws = (char*)d_ws;
  half_t* xt    = (half_t*)(ws + XT_OFF);
  half_t* hs0   = (half_t*)(ws + HS0_OFF);
  float*  wcomb = (float*)(ws + WC_OFF);
  float*  biasc = (float*)(ws + BC_OFF);

  k_prep <<<dim3(1),     dim3(512), 0, stream>>>(cheb_w0, cheb_w1, cheb_b, wih0, bih0, bhh0, wcomb, biasc);
  k_xpose<<<dim3(27000), dim3(256), 0, stream>>>(x1, xt);
  k_lstm0<<<dim3(256),   dim3(512), 0, stream>>>(xt, wcomb, biasc, whh0, hs0);
  k_lstm1<<<dim3(256),   dim3(512), 0, stream>>>(hs0, wih1, whh1, bih1, bhh1, fc_w, fc_b, (float*)d_out);
}

// Round 3
// 808.191 us; speedup vs baseline: 1.1547x; 1.1229x over previous
//
#include <hip/hip_runtime.h>
#include <hip/hip_fp16.h>

typedef _Float16 half_t;
typedef _Float16 half8 __attribute__((ext_vector_type(8)));
typedef float floatx4 __attribute__((ext_vector_type(4)));

// ---- sizes ----
#define T_STEPS 300
#define NMB     1024           // N*M batch
#define XT_ROWS (T_STEPS*NMB + 16)   // +16 pad so A-fragment row reads never fault

// ws layout (bytes)
#define XT_OFF   0ULL
#define XT_BYTES ((unsigned long long)XT_ROWS*64*2)          // 39,323,648
#define HS0_OFF  (XT_OFF + XT_BYTES)
#define HS0_BYTES ((unsigned long long)XT_ROWS*128*2)        // 78,647,296
#define WC_OFF   (HS0_OFF + HS0_BYTES)                       // 117,970,944
#define WC_BYTES (512ULL*64*4)
#define BC_OFF   (WC_OFF + WC_BYTES)                         // 118,102,016

// L_hat = -D^-1/2 A D^-1/2 for the hardcoded 15-node skeleton (row=dst, col=src)
#define S2 0.70710678118654752f
#define QH 0.5f
#define UU 0.40824829046386302f
#define TH 0.33333333333333333f
__constant__ float LHAT[225] = {
  0,0,-S2,0,0,0,0,0,0,0,0,0,0,0,0,
  0,0,0,-S2,0,0,0,0,0,0,0,0,0,0,0,
  -S2,0,0,0,-QH,0,0,0,0,0,0,0,0,0,0,
  0,-S2,0,0,0,-QH,0,0,0,0,0,0,0,0,0,
  0,0,-QH,0,0,0,0,0,0,0,0,0,0,0,-UU,
  0,0,0,-QH,0,0,0,0,0,0,0,0,0,0,-UU,
  0,0,0,0,0,0,0,0,-S2,0,0,0,0,0,0,
  0,0,0,0,0,0,0,0,0,-S2,0,0,0,0,0,
  0,0,0,0,0,0,-S2,0,0,0,-QH,0,0,0,0,
  0,0,0,0,0,0,0,-S2,0,0,0,-QH,0,0,0,
  0,0,0,0,0,0,0,0,-QH,0,0,0,0,-UU,0,
  0,0,0,0,0,0,0,0,0,-QH,0,0,0,-UU,0,
  0,0,0,0,0,0,0,0,0,0,0,0,0,0,0,
  0,0,0,0,0,0,0,0,0,0,-UU,-UU,0,0,0,
  0,0,0,0,-UU,-UU,0,0,0,0,0,0,0,-TH,0
};

// Fast gate math: v_exp_f32 + v_rcp_f32 (approx, ~1 ulp).
__device__ __forceinline__ float frcp(float x)  { return __builtin_amdgcn_rcpf(x); }
__device__ __forceinline__ float fsig(float x)  { return frcp(1.f + __expf(-x)); }
__device__ __forceinline__ float ftanh(float x) { return 2.f*frcp(1.f + __expf(-2.f*x)) - 1.f; }

__device__ __forceinline__ half8 load_w8(const float* p) {
  const float4* q = (const float4*)p;
  float4 a = q[0], b = q[1];
  half8 f;
  f[0]=(half_t)a.x; f[1]=(half_t)a.y; f[2]=(half_t)a.z; f[3]=(half_t)a.w;
  f[4]=(half_t)b.x; f[5]=(half_t)b.y; f[6]=(half_t)b.z; f[7]=(half_t)b.w;
  return f;
}

// ---- K0: fold ChebConv into the layer-0 input projection: Wcomb[512][64], bias_comb[512]
__global__ void k_prep(const float* __restrict__ w0, const float* __restrict__ w1,
                       const float* __restrict__ cb, const float* __restrict__ wih0,
                       const float* __restrict__ bih0, const float* __restrict__ bhh0,
                       float* __restrict__ wcomb, float* __restrict__ biasc) {
  const int n = threadIdx.x; // 512 threads, 1 block
  float wrow[45];
  #pragma unroll
  for (int i=0;i<45;i++) wrow[i] = wih0[n*45+i];
  float P[45];
  #pragma unroll
  for (int i=0;i<15;i++)
    #pragma unroll
    for (int c=0;c<3;c++) {
      float s = 0.f;
      #pragma unroll
      for (int cp=0;cp<3;cp++) s += wrow[i*3+cp]*w1[cp*3+c];
      P[i*3+c] = s;
    }
  #pragma unroll
  for (int j=0;j<15;j++)
    #pragma unroll
    for (int c=0;c<3;c++) {
      float s = 0.f;
      #pragma unroll
      for (int cp=0;cp<3;cp++) s += wrow[j*3+cp]*w0[cp*3+c];
      #pragma unroll
      for (int i=0;i<15;i++) s += LHAT[i*15+j]*P[i*3+c];
      wcomb[n*64 + j*3+c] = s;
    }
  for (int k=45;k<64;k++) wcomb[n*64+k] = 0.f;
  float b = bih0[n] + bhh0[n];
  #pragma unroll
  for (int i=0;i<15;i++)
    #pragma unroll
    for (int cp=0;cp<3;cp++) b += wrow[i*3+cp]*cb[cp];
  biasc[n] = b;
}

// ---- K0b: x1 [N,C,T,V,M] fp32 -> xt [t*1024+nm][64] fp16 (features v*3+c, 45 valid)
__global__ void k_xpose(const float* __restrict__ x1, half_t* __restrict__ xt) {
  const int id = blockIdx.x*256 + threadIdx.x;   // exactly 512*3*300*15 = 6,912,000
  const int v  = id % 15;
  const int r1 = id / 15;
  const int t  = r1 % 300;
  const int r2 = r1 / 300;
  const int c  = r2 % 3;
  const int n  = r2 / 3;
  const float2 f = ((const float2*)x1)[id];      // m=0,1 pair, coalesced
  const size_t row = (size_t)t*NMB + n*2;
  xt[row*64     + v*3 + c] = (half_t)f.x;
  xt[(row+1)*64 + v*3 + c] = (half_t)f.y;
}

// ---- KA: layer-0 LSTM recurrence. 256 WGs x 512 threads; 4 batch rows per WG.
// Wave w owns hidden cols w*16+l16; its 4 MFMA N-tiles are the 4 gates (i,f,g,o)
// of those cols, so the nonlinearity runs in-register on quad-0 lanes (c-state in
// VGPRs). Single barrier per step; h double-buffered in LDS.
__launch_bounds__(512, 2)
__global__ void k_lstm0(const half_t* __restrict__ xt, const float* __restrict__ wcomb,
                        const float* __restrict__ biasc, const float* __restrict__ whh0,
                        half_t* __restrict__ hs0) {
  __shared__ __align__(16) half_t h_lds[2][16*136];
  const int tid = threadIdx.x;
  const int wave = tid>>6, lane = tid&63, quad = lane>>4, l16 = lane&15;
  const int nm0 = blockIdx.x*4;
  for (int i=tid; i<2*16*136; i+=512) h_lds[0][i] = (half_t)0.f;

  half8 whhF[4][4];  // [nt=gate][kc] B-frags: B[k][n] = Whh0[gcol][k]
  half8 wcF [4][2];
  float bsum[4];
  #pragma unroll
  for (int nt=0; nt<4; nt++) {
    const int gcol = nt*128 + wave*16 + l16;
    #pragma unroll
    for (int kc=0; kc<4; kc++) whhF[nt][kc] = load_w8(whh0 + gcol*128 + kc*32 + quad*8);
    #pragma unroll
    for (int kc=0; kc<2; kc++) wcF[nt][kc]  = load_w8(wcomb + gcol*64 + kc*32 + quad*8);
    bsum[nt] = biasc[gcol];
  }
  float cst[4] = {0.f,0.f,0.f,0.f};   // valid on quad-0 lanes only

  half8 xv[2], xvn[2];
  { const size_t row = (size_t)nm0 + l16;   // t = 0
    xv[0] = *(const half8*)(xt + row*64 +      quad*8);
    xv[1] = *(const half8*)(xt + row*64 + 32 + quad*8);
  }
  __syncthreads();

  for (int t=0; t<T_STEPS; t++) {
    const int tn = (t+1 < T_STEPS) ? t+1 : T_STEPS-1;
    { const size_t row = (size_t)tn*NMB + nm0 + l16;     // prefetch next step's x
      xvn[0] = *(const half8*)(xt + row*64 +      quad*8);
      xvn[1] = *(const half8*)(xt + row*64 + 32 + quad*8);
    }
    half8 hA[4];
    #pragma unroll
    for (int kc=0; kc<4; kc++)
      hA[kc] = *(const half8*)(&h_lds[t&1][0] + l16*136 + kc*32 + quad*8);

    floatx4 acc[4];
    #pragma unroll
    for (int nt=0; nt<4; nt++) {
      floatx4 a = {0.f,0.f,0.f,0.f};
      a = __builtin_amdgcn_mfma_f32_16x16x32_f16(xv[0], wcF[nt][0], a, 0,0,0);
      a = __builtin_amdgcn_mfma_f32_16x16x32_f16(xv[1], wcF[nt][1], a, 0,0,0);
      #pragma unroll
      for (int kc=0; kc<4; kc++)
        a = __builtin_amdgcn_mfma_f32_16x16x32_f16(hA[kc], whhF[nt][kc], a, 0,0,0);
      acc[nt] = a;
    }
    if (quad == 0) {   // rows 0..3 of the C-tile = batch rows; all 4 gates in-lane
      #pragma unroll
      for (int reg=0; reg<4; reg++) {
        const float gi = acc[0][reg] + bsum[0];
        const float gf = acc[1][reg] + bsum[1];
        const float gg = acc[2][reg] + bsum[2];
        const float go = acc[3][reg] + bsum[3];
        cst[reg] = fsig(gf)*cst[reg] + fsig(gi)*ftanh(gg);
        const half_t h = (half_t)(fsig(go)*ftanh(cst[reg]));
        h_lds[(t+1)&1][reg*136 + wave*16 + l16] = h;
        hs0[((size_t)t*NMB + nm0 + reg)*128 + wave*16 + l16] = h;
      }
    }
    xv[0] = xvn[0]; xv[1] = xvn[1];
    __syncthreads();
  }
}

// ---- KB: layer-1 LSTM (input GEMM on the fly from hs0) + FC + softmax
__launch_bounds__(512, 2)
__global__ void k_lstm1(const half_t* __restrict__ hs0, const float* __restrict__ wih1,
                        const float* __restrict__ whh1, const float* __restrict__ bih1,
                        const float* __restrict__ bhh1, const float* __restrict__ fcw,
                        const float* __restrict__ fcb, float* __restrict__ out) {
  __shared__ __align__(16) half_t h_lds[2][16*136];
  __shared__ float logits_lds[240];
  const int tid = threadIdx.x;
  const int wave = tid>>6, lane = tid&63, quad = lane>>4, l16 = lane&15;
  const int nm0 = blockIdx.x*4;
  for (int i=tid; i<2*16*136; i+=512) h_lds[0][i] = (half_t)0.f;

  half8 wxF[4][4], whF[4][4];
  float bsum[4];
  #pragma unroll
  for (int nt=0; nt<4; nt++) {
    const int gcol = nt*128 + wave*16 + l16;
    #pragma unroll
    for (int kc=0; kc<4; kc++) {
      wxF[nt][kc] = load_w8(wih1 + gcol*128 + kc*32 + quad*8);
      whF[nt][kc] = load_w8(whh1 + gcol*128 + kc*32 + quad*8);
    }
    bsum[nt] = bih1[gcol] + bhh1[gcol];
  }
  float cst[4] = {0.f,0.f,0.f,0.f};

  half8 xv[4], xvn[4];
  { const size_t row = (size_t)nm0 + l16;   // t = 0
    #pragma unroll
    for (int kc=0; kc<4; kc++) xv[kc] = *(const half8*)(hs0 + row*128 + kc*32 + quad*8);
  }
  __syncthreads();

  for (int t=0; t<T_STEPS; t++) {
    const int tn = (t+1 < T_STEPS) ? t+1 : T_STEPS-1;
    { const size_t row = (size_t)tn*NMB + nm0 + l16;
      #pragma unroll
      for (int kc=0; kc<4; kc++) xvn[kc] = *(const half8*)(hs0 + row*128 + kc*32 + quad*8);
    }
    half8 hA[4];
    #pragma unroll
    for (int kc=0; kc<4; kc++)
      hA[kc] = *(const half8*)(&h_lds[t&1][0] + l16*136 + kc*32 + quad*8);

    floatx4 acc[4];
    #pragma unroll
    for (int nt=0; nt<4; nt++) {
      floatx4 a = {0.f,0.f,0.f,0.f};
      #pragma unroll
      for (int kc=0; kc<4; kc++)
        a = __builtin_amdgcn_mfma_f32_16x16x32_f16(xv[kc], wxF[nt][kc], a, 0,0,0);
      #pragma unroll
      for (int kc=0; kc<4; kc++)
        a = __builtin_amdgcn_mfma_f32_16x16x32_f16(hA[kc], whF[nt][kc], a, 0,0,0);
      acc[nt] = a;
    }
    if (quad == 0) {
      #pragma unroll
      for (int reg=0; reg<4; reg++) {
        const float gi = acc[0][reg] + bsum[0];
        const float gf = acc[1][reg] + bsum[1];
        const float gg = acc[2][reg] + bsum[2];
        const float go = acc[3][reg] + bsum[3];
        cst[reg] = fsig(gf)*cst[reg] + fsig(gi)*ftanh(gg);
        h_lds[(t+1)&1][reg*136 + wave*16 + l16] = (half_t)(fsig(go)*ftanh(cst[reg]));
      }
    }
    #pragma unroll
    for (int kc=0; kc<4; kc++) xv[kc] = xvn[kc];
    __syncthreads();
  }

  // FC (60 classes) + softmax; h_last (t=299) lives in h_lds[0] rows 0..3
  if (tid < 240) {
    const int r2 = tid/60, cls = tid%60;
    float s = fcb[cls];
    for (int k2=0; k2<128; k2++) s += (float)h_lds[0][r2*136+k2] * fcw[cls*128+k2];
    logits_lds[r2*60+cls] = s;
  }
  __syncthreads();
  if (tid < 4) {
    float m = -1e30f;
    for (int j=0; j<60; j++) m = fmaxf(m, logits_lds[tid*60+j]);
    float s = 0.f;
    for (int j=0; j<60; j++) s += __expf(logits_lds[tid*60+j]-m);
    const float inv = frcp(s);
    for (int j=0; j<60; j++) out[(nm0+tid)*60+j] = __expf(logits_lds[tid*60+j]-m)*inv;
  }
}

extern "C" void kernel_launch(void* const* d_in, const int* in_sizes, int n_in,
                              void* d_out, int out_size, void* d_ws, size_t ws_size,
                              hipStream_t stream) {
  const float* x1      = (const float*)d_in[0];
  const float* cheb_w0 = (const float*)d_in[2];
  const float* cheb_w1 = (const float*)d_in[3];
  const float* cheb_b  = (const float*)d_in[4];
  const float* wih0    = (const float*)d_in[5];
  const float* whh0    = (const float*)d_in[6];
  const float* bih0    = (const float*)d_in[7];
  const float* bhh0    = (const float*)d_in[8];
  const float* wih1    = (const float*)d_in[9];
  const float* whh1    = (const float*)d_in[10];
  const float* bih1    = (const float*)d_in[11];
  const float* bhh1    = (const float*)d_in[12];
  const float* fc_w    = (const float*)d_in[13];
  const float* fc_b    = (const float*)d_in[14];

  char* ws = (char*)d_ws;
  half_t* xt    = (half_t*)(ws + XT_OFF);
  half_t* hs0   = (half_t*)(ws + HS0_OFF);
  float*  wcomb = (float*)(ws + WC_OFF);
  float*  biasc = (float*)(ws + BC_OFF);

  k_prep <<<dim3(1),     dim3(512), 0, stream>>>(cheb_w0, cheb_w1, cheb_b, wih0, bih0, bhh0, wcomb, biasc);
  k_xpose<<<dim3(27000), dim3(256), 0, stream>>>(x1, xt);
  k_lstm0<<<dim3(256),   dim3(512), 0, stream>>>(xt, wcomb, biasc, whh0, hs0);
  k_lstm1<<<dim3(256),   dim3(512), 0, stream>>>(hs0, wih1, whh1, bih1, bhh1, fc_w, fc_b, (float*)d_out);
}